// Round 9
// baseline (112.503 us; speedup 1.0000x reference)
//
#include <hip/hip_runtime.h>

// Problem constants: B=256, T=256, H=768, S=130
#define BB 256
#define TT 256
#define HH 768
#define SS 130
#define SPAD 160                 // padded S rows per B k-chunk tile
#define NCH 12                   // 768 / 64
#define CHB (SPAD * 128)         // bytes per B chunk tile = 20480

typedef __attribute__((ext_vector_type(8))) __bf16 bf16x8;
typedef __attribute__((ext_vector_type(4))) float f32x4;

__device__ __forceinline__ unsigned f2bf(float f) {
    unsigned x = __builtin_bit_cast(unsigned, f);
    x = (x + 0x7FFFu + ((x >> 16) & 1u)) >> 16;
    return x & 0xFFFFu;
}

// ---- prep: [blocks 0..47] W -> wsT2 swizzled bf16 tiles; [48..303] seg -> bounds ----
// wsT2 tile kc: row s (160 rows x 128 B), 16B-chunk j stored at slot j^(s&7).
__global__ __launch_bounds__(256)
void prep_kernel(const float* __restrict__ W, unsigned* __restrict__ wsT2,
                 const int* __restrict__ seg, int2* __restrict__ bounds)
{
    __shared__ __align__(16) char pm[64 * 41 * 4];   // 10496 B, dual-use
    const int tid = threadIdx.x;

    if (blockIdx.x < 48) {
        float* Wl = (float*)pm;                       // [64 k][41] s-local
        const int kc = blockIdx.x >> 2;
        const int qq = blockIdx.x & 3;
        const int sbase = qq * 40;
        const int scv = (SS - sbase < 40) ? (SS - sbase) : 40;   // 40,40,40,10
        for (int i = tid; i < 64 * 40; i += 256) {
            int r = i / 40, c = i - r * 40;
            if (c < scv) Wl[r * 41 + c] = W[(size_t)(kc * 64 + r) * SS + sbase + c];
        }
        __syncthreads();
        for (int u = tid; u < 40 * 32; u += 256) {
            int sl = u >> 5, s = sbase + sl, qp = u & 31;
            int ql = (((qp >> 2) ^ (s & 7)) << 2) | (qp & 3);    // logical k-pair
            unsigned v = 0;
            if (sl < scv)
                v = f2bf(Wl[(2 * ql) * 41 + sl]) | (f2bf(Wl[(2 * ql + 1) * 41 + sl]) << 16);
            wsT2[kc * 5120 + s * 32 + qp] = v;                   // coalesced
        }
    } else {
        int* segl = (int*)pm;                 // [256]
        int* st_s = segl + 256;
        int* cn_s = segl + 512;
        const int b = blockIdx.x - 48;
        segl[tid] = seg[b * TT + tid];
        st_s[tid] = 0;
        cn_s[tid] = 0;
        __syncthreads();
        int id = segl[tid];
        if (tid == 0 || segl[tid - 1] != id) {   // run starts (seg row-sorted)
            int e = tid;
            while (e + 1 < TT && segl[e + 1] == id) ++e;
            st_s[id] = tid;
            cn_s[id] = e - tid + 1;
        }
        __syncthreads();
        bounds[b * TT + tid] = make_int2(st_s[tid], cn_s[tid]);
    }
}

// ---- main: 128-token GEMM (B DMA dbuf + vmcnt(8); A depth-2 named regs) with
// fused in-block ragged segment-mean. grid 512 = (b, half). ----
__global__ __launch_bounds__(256, 2)
void main_kernel(const float* __restrict__ hidden,
                 const char* __restrict__ wsT2,
                 const float* __restrict__ bias,
                 const int* __restrict__ seg,
                 const int2* __restrict__ bounds,
                 float* __restrict__ pbuf,
                 float* __restrict__ out)
{
    __shared__ __align__(16) char Blds[2 * CHB];   // 40960 B (C merge buffer aliases)
    __shared__ float biasl[SS];

    const int tid  = threadIdx.x;
    const int wv   = tid >> 6;
    const int lane = tid & 63;
    const int r16  = lane & 15;
    const int g    = lane >> 4;
    const int b    = blockIdx.x >> 1;
    const int h    = blockIdx.x & 1;
    const int t0   = h << 7;                       // 128-token half

    if (tid < SS) biasl[tid] = bias[tid];

    const float* A0p = hidden + (size_t)b * (TT + 1) * HH
                     + (size_t)(1 + t0 + wv * 32 + r16) * HH + g * 8;
    const float* A1p = A0p + (size_t)16 * HH;

    f32x4 acc[2][9];
    #pragma unroll
    for (int m = 0; m < 2; ++m)
        #pragma unroll
        for (int j = 0; j < 9; ++j) acc[m][j] = (f32x4){0.f, 0.f, 0.f, 0.f};

    const int xv = g ^ (r16 & 7);
    const int x0 = xv << 4;
    const int x1 = x0 ^ 64;

#define BDMA(KB_, PAR_)                                                                  \
    do {                                                                                  \
        const char* gs_ = wsT2 + (size_t)(KB_) * CHB + wv * 5120 + lane * 16;             \
        unsigned* ld_ = (unsigned*)(Blds + (PAR_) * CHB + wv * 5120);                     \
        _Pragma("unroll")                                                                 \
        for (int i_ = 0; i_ < 5; ++i_)                                                    \
            __builtin_amdgcn_global_load_lds((const unsigned*)(gs_ + i_ * 1024),          \
                                             ld_ + i_ * 256, 16, 0, 0);                   \
    } while (0)

#define ALOAD(E0, E1, E2, E3, E4, E5, E6, E7, KA_)                                        \
    do {                                                                                  \
        const float* a0_ = A0p + (KA_) * 64;                                              \
        const float* a1_ = A1p + (KA_) * 64;                                              \
        E0 = *(const float4*)(a0_);      E1 = *(const float4*)(a0_ + 4);                  \
        E2 = *(const float4*)(a0_ + 32); E3 = *(const float4*)(a0_ + 36);                 \
        E4 = *(const float4*)(a1_);      E5 = *(const float4*)(a1_ + 4);                  \
        E6 = *(const float4*)(a1_ + 32); E7 = *(const float4*)(a1_ + 36);                 \
    } while (0)

#define CHUNK(E0, E1, E2, E3, E4, E5, E6, E7, KC_, PAR_)                                  \
    do {                                                                                  \
        union { unsigned u[4]; bf16x8 v; } af00, af01, af10, af11;                        \
        asm("v_cvt_pk_bf16_f32 %0, %1, %2" : "=v"(af00.u[0]) : "v"(E0.x), "v"(E0.y));     \
        asm("v_cvt_pk_bf16_f32 %0, %1, %2" : "=v"(af00.u[1]) : "v"(E0.z), "v"(E0.w));     \
        asm("v_cvt_pk_bf16_f32 %0, %1, %2" : "=v"(af00.u[2]) : "v"(E1.x), "v"(E1.y));     \
        asm("v_cvt_pk_bf16_f32 %0, %1, %2" : "=v"(af00.u[3]) : "v"(E1.z), "v"(E1.w));     \
        asm("v_cvt_pk_bf16_f32 %0, %1, %2" : "=v"(af01.u[0]) : "v"(E2.x), "v"(E2.y));     \
        asm("v_cvt_pk_bf16_f32 %0, %1, %2" : "=v"(af01.u[1]) : "v"(E2.z), "v"(E2.w));     \
        asm("v_cvt_pk_bf16_f32 %0, %1, %2" : "=v"(af01.u[2]) : "v"(E3.x), "v"(E3.y));     \
        asm("v_cvt_pk_bf16_f32 %0, %1, %2" : "=v"(af01.u[3]) : "v"(E3.z), "v"(E3.w));     \
        asm("v_cvt_pk_bf16_f32 %0, %1, %2" : "=v"(af10.u[0]) : "v"(E4.x), "v"(E4.y));     \
        asm("v_cvt_pk_bf16_f32 %0, %1, %2" : "=v"(af10.u[1]) : "v"(E4.z), "v"(E4.w));     \
        asm("v_cvt_pk_bf16_f32 %0, %1, %2" : "=v"(af10.u[2]) : "v"(E5.x), "v"(E5.y));     \
        asm("v_cvt_pk_bf16_f32 %0, %1, %2" : "=v"(af10.u[3]) : "v"(E5.z), "v"(E5.w));     \
        asm("v_cvt_pk_bf16_f32 %0, %1, %2" : "=v"(af11.u[0]) : "v"(E6.x), "v"(E6.y));     \
        asm("v_cvt_pk_bf16_f32 %0, %1, %2" : "=v"(af11.u[1]) : "v"(E6.z), "v"(E6.w));     \
        asm("v_cvt_pk_bf16_f32 %0, %1, %2" : "=v"(af11.u[2]) : "v"(E7.x), "v"(E7.y));     \
        asm("v_cvt_pk_bf16_f32 %0, %1, %2" : "=v"(af11.u[3]) : "v"(E7.z), "v"(E7.w));     \
        asm volatile("s_waitcnt vmcnt(8)" ::: "memory");                                  \
        __builtin_amdgcn_s_barrier();                                                     \
        __builtin_amdgcn_sched_barrier(0);                                                \
        {                                                                                 \
            const int kb_ = ((KC_) + 1 < NCH) ? (KC_) + 1 : NCH - 1;                      \
            BDMA(kb_, 1 - (PAR_));                                                        \
        }                                                                                 \
        {                                                                                 \
            const int ka_ = ((KC_) + 2 < NCH) ? (KC_) + 2 : NCH - 1;                      \
            ALOAD(E0, E1, E2, E3, E4, E5, E6, E7, ka_);                                   \
        }                                                                                 \
        __builtin_amdgcn_sched_barrier(0);                                                \
        {                                                                                 \
            const char* base_ = Blds + (PAR_) * CHB + r16 * 128;                          \
            _Pragma("unroll")                                                             \
            for (int nt = 0; nt < 9; ++nt) {                                              \
                bf16x8 b0_ = *(const bf16x8*)(base_ + nt * 2048 + x0);                    \
                acc[0][nt] = __builtin_amdgcn_mfma_f32_16x16x32_bf16(af00.v, b0_,         \
                                                                    acc[0][nt], 0, 0, 0); \
                acc[1][nt] = __builtin_amdgcn_mfma_f32_16x16x32_bf16(af10.v, b0_,         \
                                                                    acc[1][nt], 0, 0, 0); \
            }                                                                             \
            _Pragma("unroll")                                                             \
            for (int nt = 0; nt < 9; ++nt) {                                              \
                bf16x8 b1_ = *(const bf16x8*)(base_ + nt * 2048 + x1);                    \
                acc[0][nt] = __builtin_amdgcn_mfma_f32_16x16x32_bf16(af01.v, b1_,         \
                                                                    acc[0][nt], 0, 0, 0); \
                acc[1][nt] = __builtin_amdgcn_mfma_f32_16x16x32_bf16(af11.v, b1_,         \
                                                                    acc[1][nt], 0, 0, 0); \
            }                                                                             \
        }                                                                                 \
    } while (0)

    // prologue: B_0 DMA, A_0 (even set), A_1 (odd set)
    BDMA(0, 0);
    float4 e0, e1, e2, e3, e4, e5, e6, e7;
    float4 o0, o1, o2, o3, o4, o5, o6, o7;
    ALOAD(e0, e1, e2, e3, e4, e5, e6, e7, 0);
    ALOAD(o0, o1, o2, o3, o4, o5, o6, o7, 1);

    #pragma unroll 1
    for (int kp = 0; kp < NCH / 2; ++kp) {
        CHUNK(e0, e1, e2, e3, e4, e5, e6, e7, 2 * kp, 0);
        CHUNK(o0, o1, o2, o3, o4, o5, o6, o7, 2 * kp + 1, 1);
    }
#undef CHUNK
#undef ALOAD
#undef BDMA

    asm volatile("s_waitcnt vmcnt(0)" ::: "memory");   // drain clamped tail DMAs
    __syncthreads();                                    // all LDS reads/DMA done

    // ---- fused merge: C chunk [128][50] aliases Blds ----
    float* C = (float*)Blds;
    const int  w   = tid;
    const int2 bc  = bounds[b * TT + w];
    const int  wsp = seg[b * TT + 127];
    const bool strad = (wsp == seg[b * TT + 128]);     // run of wsp crosses t=128
    const bool isst  = strad && (w == wsp);
    const bool mine  = (h == 0) ? (w <= wsp) : (w > wsp);
    int lo = bc.x < t0 ? t0 : bc.x;
    int hi = (bc.x + bc.y > t0 + 128) ? (t0 + 128) : (bc.x + bc.y);
    const int llo = lo - t0;
    const int lhi = hi - t0;                            // empty range if cn==0 or not local
    const float inv = (bc.y > 0) ? 1.f / (float)bc.y : 0.f;

    #pragma unroll 1
    for (int ch = 0; ch < 3; ++ch) {
        #pragma unroll
        for (int m = 0; m < 2; ++m) {
            const int rbase = wv * 32 + m * 16 + g * 4;  // D row = g*4 + i
            #pragma unroll
            for (int j = 0; j < 3; ++j) {
                const int nt  = 3 * ch + j;
                const int col = j * 16 + r16;             // D col = r16
                #pragma unroll
                for (int i = 0; i < 4; ++i)
                    C[(rbase + i) * 50 + col] = acc[m][nt][i];
            }
        }
        __syncthreads();

        const int scnt = (ch < 2) ? 48 : 34;
        if (isst) {
            for (int c = 0; c < scnt; ++c) {
                float a = 0.f;
                for (int t = llo; t < lhi; ++t) a += C[t * 50 + c];
                pbuf[(b * 2 + h) * SS + ch * 48 + c] = a;      // raw partial, no bias
            }
        } else if (mine) {
            for (int c = 0; c < scnt; ++c) {
                float v = 0.f;
                if (bc.y > 0) {
                    float a = 0.f;
                    for (int t = llo; t < lhi; ++t) a += C[t * 50 + c];
                    v = a * inv + biasl[ch * 48 + c];
                }
                out[((size_t)b * SS + ch * 48 + c) * TT + w] = v;
            }
        }
        __syncthreads();
    }
}

// ---- fix-up: finalize the (at most one per row) straddle word ----
__global__ __launch_bounds__(256)
void fix_kernel(const int* __restrict__ seg, const int2* __restrict__ bounds,
                const float* __restrict__ pbuf, const float* __restrict__ bias,
                float* __restrict__ out)
{
    const int b = blockIdx.x;
    const int s = threadIdx.x;
    if (s >= SS) return;
    const int wsp = seg[b * TT + 127];
    if (wsp != seg[b * TT + 128]) return;
    const int2 bc = bounds[b * TT + wsp];
    float v = (pbuf[(b * 2) * SS + s] + pbuf[(b * 2 + 1) * SS + s]) / (float)bc.y + bias[s];
    out[((size_t)b * SS + s) * TT + wsp] = v;
}

extern "C" void kernel_launch(void* const* d_in, const int* in_sizes, int n_in,
                              void* d_out, int out_size, void* d_ws, size_t ws_size,
                              hipStream_t stream)
{
    const float* hidden = (const float*)d_in[0];  // [256, 257, 768] f32
    const float* W      = (const float*)d_in[1];  // [768, 130] f32
    const float* bias   = (const float*)d_in[2];  // [130] f32
    const int*   seg    = (const int*)d_in[3];    // [256, 256] i32 (row-sorted)
    float* out = (float*)d_out;                   // [256, 130, 256] f32

    unsigned* wsT2  = (unsigned*)d_ws;                          // 245760 B
    int2*     bounds = (int2*)((char*)d_ws + 245760);           // 524288 B
    float*    pbuf   = (float*)((char*)d_ws + 245760 + 524288); // 266240 B

    (void)in_sizes; (void)n_in; (void)ws_size; (void)out_size;

    prep_kernel<<<dim3(304), dim3(256), 0, stream>>>(W, wsT2, seg, bounds);
    main_kernel<<<dim3(512), dim3(256), 0, stream>>>(hidden, (const char*)wsT2, bias,
                                                     seg, bounds, pbuf, out);
    fix_kernel<<<dim3(256), dim3(256), 0, stream>>>(seg, bounds, pbuf, bias, out);
}